// Round 7
// baseline (689.646 us; speedup 1.0000x reference)
//
#include <hip/hip_runtime.h>

typedef __attribute__((ext_vector_type(8))) __bf16 bf16x8;
typedef __attribute__((ext_vector_type(8))) unsigned short u16x8;
typedef __attribute__((ext_vector_type(4))) unsigned short u16x4;
typedef __attribute__((ext_vector_type(4))) float f32x4;

#define N_LOCI   59412
#define T_DIM    500
#define T_PAD    512
#define N_ENC    200
#define KL       29696
#define KR       29716
#define J_PAD    59648
#define G1_S     58      // split-K chunks per compartment (58*512 >= K)

__device__ __forceinline__ unsigned short cvt1(float x) {
    __bf16 h = (__bf16)x;
    return __builtin_bit_cast(unsigned short, h);
}
__device__ __forceinline__ float bf2f(unsigned short h) {
    return __uint_as_float(((unsigned)h) << 16);
}
__device__ __forceinline__ f32x4 mfma16(u16x8 a, u16x8 b, f32x4 c) {
    return __builtin_amdgcn_mfma_f32_16x16x32_bf16(
        __builtin_bit_cast(bf16x8, a), __builtin_bit_cast(bf16x8, b), c, 0, 0, 0);
}

// ---------------------------------------------------------------------------
// K2: bf16 partials P16[g][200][512] of A = W_c @ X_slice (RAW, uncentered),
// plus (mt==0): raw-bf16 Xb[loci][512]. Tile M=128 x N=128, BK=64, 256 thr
// (4 waves 2x2, wave 64x64). B staged transposed [n][64] XOR-swizzled,
// A staged [m][64] XOR-swizzled. Grid 928 g-major: d = g*8 + slot,
// slot = mt*4 + nt (mt 0..1, nt 0..3).
// ---------------------------------------------------------------------------
__global__ __launch_bounds__(256, 4) void k2_gemm1(const float* __restrict__ X,
                                                   const float* __restrict__ WL,
                                                   const float* __restrict__ WR,
                                                   unsigned short* __restrict__ P16,
                                                   unsigned short* __restrict__ Xb) {
    const int d = blockIdx.x;
    const int g = d >> 3;          // 0..115
    const int slot = d & 7;
    const int mt = slot >> 2;      // 0..1
    const int nt = slot & 3;       // 0..3
    const int sc   = g >> 1;       // 0..57
    const int comp = g & 1;
    const int K      = comp ? KR : KL;
    const float* W   = comp ? WR : WL;
    const int xbase  = comp ? KL : 0;
    const int m0 = mt * 128;
    const int n0 = nt * 128;
    const bool emit = (mt == 0);

    __shared__ unsigned short As[128 * 64];
    __shared__ unsigned short Bs[128 * 64];

    const int t = threadIdx.x, lane = t & 63, wid = t >> 6;
    const int wm = wid >> 1, wn = wid & 1;
    const int lr = lane & 15, lg = lane >> 4;

    f32x4 acc[4][4];
    #pragma unroll
    for (int i = 0; i < 4; ++i)
        #pragma unroll
        for (int j = 0; j < 4; ++j) {
            f32x4 z = {0.f, 0.f, 0.f, 0.f};
            acc[i][j] = z;
        }

    const int nsteps = (comp && sc == G1_S - 1) ? 9 : 8;

    // A staging: row am (0..127), 32-k segment aseg
    const int am = t >> 1, aseg = t & 1;
    const int arow = (m0 + am < N_ENC) ? (m0 + am) : (N_ENC - 1);
    const float* wrow = W + (size_t)arow * K;
    const int akey = ((am >> 2) & 7) << 3;
    // B staging: k-quad kq (4 rows), col thread tc (8 cols)
    const int kq = t >> 4, tc = t & 15;

    u16x8 ha[4];
    unsigned short hv[4][8];

    auto load_tiles = [&](int st) {
        const int k0 = sc * 512 + st * 64;
        // ---- A: 32 k per thread ----
        {
            const int kb = k0 + aseg * 32;
            float av[32];
            if (kb + 31 < K) {
                #pragma unroll
                for (int f = 0; f < 8; ++f) {
                    const float4 v = *(const float4*)(wrow + kb + f * 4);
                    av[f * 4 + 0] = v.x; av[f * 4 + 1] = v.y;
                    av[f * 4 + 2] = v.z; av[f * 4 + 3] = v.w;
                }
            } else {
                #pragma unroll
                for (int j = 0; j < 32; ++j)
                    av[j] = (kb + j < K) ? wrow[kb + j] : 0.0f;
            }
            #pragma unroll
            for (int q = 0; q < 4; ++q) {
                u16x8 hh;
                #pragma unroll
                for (int j = 0; j < 8; ++j) hh[j] = cvt1(av[q * 8 + j]);
                ha[q] = hh;
            }
        }
        // ---- B: 4 rows x 8 cols per thread ----
        #pragma unroll
        for (int r = 0; r < 4; ++r) {
            const int krel = k0 + kq * 4 + r;
            const bool kok = krel < K;
            const float* xr = X + (size_t)(xbase + krel) * T_DIM;
            const int c = n0 + tc * 8;
            float xv[8];
            if (kok && c + 7 < T_DIM) {
                const float4 v0 = *(const float4*)(xr + c);
                const float4 v1 = *(const float4*)(xr + c + 4);
                xv[0] = v0.x; xv[1] = v0.y; xv[2] = v0.z; xv[3] = v0.w;
                xv[4] = v1.x; xv[5] = v1.y; xv[6] = v1.z; xv[7] = v1.w;
            } else {
                #pragma unroll
                for (int j = 0; j < 8; ++j)
                    xv[j] = (kok && c + j < T_DIM) ? xr[c + j] : 0.0f;
            }
            #pragma unroll
            for (int j = 0; j < 8; ++j) hv[r][j] = cvt1(xv[j]);
        }
    };

    auto write_stage = [&](int st) {
        #pragma unroll
        for (int q = 0; q < 4; ++q)
            *(u16x8*)&As[am * 64 + ((aseg * 32 + q * 8) ^ akey)] = ha[q];
        #pragma unroll
        for (int j = 0; j < 8; ++j) {
            const int nl = tc * 8 + j;
            const int key = (((nl >> 2) ^ (nl >> 5)) & 7) << 3;
            u16x4 w4 = { hv[0][j], hv[1][j], hv[2][j], hv[3][j] };
            *(u16x4*)&Bs[nl * 64 + ((kq * 4) ^ key)] = w4;
        }
        if (emit) {
            const int k0 = sc * 512 + st * 64;
            #pragma unroll
            for (int r = 0; r < 4; ++r) {
                const int krel = k0 + kq * 4 + r;
                if (krel < K) {
                    u16x8 hh;
                    #pragma unroll
                    for (int j = 0; j < 8; ++j) hh[j] = hv[r][j];
                    *(u16x8*)&Xb[(size_t)(xbase + krel) * T_PAD + n0 + tc * 8] = hh;
                }
            }
        }
    };

    load_tiles(0);
    for (int st = 0; st < nsteps; ++st) {
        write_stage(st);
        __syncthreads();
        if (st + 1 < nsteps) load_tiles(st + 1);   // reg prefetch
        #pragma unroll
        for (int h = 0; h < 2; ++h) {
            u16x8 af[4], bf[4];
            #pragma unroll
            for (int mf = 0; mf < 4; ++mf) {
                const int m = wm * 64 + mf * 16 + lr;
                af[mf] = *(const u16x8*)&As[m * 64 + ((h * 32 + lg * 8) ^ (((m >> 2) & 7) << 3))];
            }
            #pragma unroll
            for (int nf = 0; nf < 4; ++nf) {
                const int nl = wn * 64 + nf * 16 + lr;
                const int key = (((nl >> 2) ^ (nl >> 5)) & 7) << 3;
                bf[nf] = *(const u16x8*)&Bs[nl * 64 + ((h * 32 + lg * 8) ^ key)];
            }
            #pragma unroll
            for (int mf = 0; mf < 4; ++mf)
                #pragma unroll
                for (int nf = 0; nf < 4; ++nf)
                    acc[mf][nf] = mfma16(af[mf], bf[nf], acc[mf][nf]);
        }
        __syncthreads();
    }

    unsigned short* Pb = P16 + (size_t)g * (200 * 512);
    #pragma unroll
    for (int mf = 0; mf < 4; ++mf)
        #pragma unroll
        for (int rr = 0; rr < 4; ++rr) {
            const int m = m0 + wm * 64 + mf * 16 + lg * 4 + rr;
            if (m < N_ENC) {
                #pragma unroll
                for (int nf = 0; nf < 4; ++nf) {
                    const int n = n0 + wn * 64 + nf * 16 + lr;
                    Pb[(size_t)m * 512 + n] = cvt1(acc[mf][nf][rr]);
                }
            }
        }
}

// ---------------------------------------------------------------------------
// K3: sum bf16 split-K partials (slice = s2*2 + comp) -> raw A row;
// store RAW bf16 Ab [512][512] (pad zero) + astat=(mu, 1/||Ac||).
// ---------------------------------------------------------------------------
__global__ __launch_bounds__(256) void k3_astats(const unsigned short* __restrict__ P16,
                                                 unsigned short* __restrict__ Ab,
                                                 float2* __restrict__ astat) {
    const int r = blockIdx.x;   // 0..511
    const int t = threadIdx.x;  // 0..255
    unsigned short* out = Ab + (size_t)r * T_PAD;
    if (r >= 2 * N_ENC) {
        out[t] = 0; out[t + 256] = 0;
        if (t == 0) astat[r] = make_float2(0.0f, 0.0f);
        return;
    }
    const int comp = (r >= N_ENC) ? 1 : 0;
    const int m = r - comp * N_ENC;
    float a1 = 0.0f, a2 = 0.0f;
    for (int s2 = 0; s2 < G1_S; ++s2) {
        const unsigned short* Pb = P16 + ((size_t)(s2 * 2 + comp) * 200 + m) * 512;
        a1 += bf2f(Pb[t]);
        a2 += bf2f(Pb[t + 256]);
    }
    const bool v2ok = (t + 256) < T_DIM;
    const float b2 = v2ok ? a2 : 0.0f;
    float s = a1 + b2;
    float q = a1 * a1 + b2 * b2;
    #pragma unroll
    for (int off = 32; off; off >>= 1) {
        s += __shfl_xor(s, off);
        q += __shfl_xor(q, off);
    }
    __shared__ float ls[4], lq[4];
    if ((t & 63) == 0) { ls[t >> 6] = s; lq[t >> 6] = q; }
    __syncthreads();
    const float S = ls[0] + ls[1] + ls[2] + ls[3];
    const float Q = lq[0] + lq[1] + lq[2] + lq[3];
    const float mean = S * (1.0f / 500.0f);
    const float iv   = rsqrtf(Q - 500.0f * mean * mean);
    out[t] = cvt1(a1);
    out[t + 256] = v2ok ? cvt1(a2) : (unsigned short)0;
    if (t == 0) astat[r] = make_float2(mean, iv);
}

// ---------------------------------------------------------------------------
// K1x: per-locus stats from raw bf16 Xb: xstat = (mu, 1/||xc||).
// 465 blocks x 4 waves; each wave streams 32 consecutive rows.
// ---------------------------------------------------------------------------
__global__ __launch_bounds__(256) void k1_xstat(const unsigned short* __restrict__ Xb,
                                                float2* __restrict__ xstat) {
    const int w    = threadIdx.x >> 6;
    const int lane = threadIdx.x & 63;
    const int rbase = blockIdx.x * 128 + w * 32;
    for (int i = 0; i < 32; ++i) {
        const int row = rbase + i;
        if (row >= N_LOCI) return;   // uniform within wave
        const u16x8 v = *(const u16x8*)(Xb + (size_t)row * T_PAD + lane * 8);
        float s = 0.0f, q = 0.0f;
        #pragma unroll
        for (int j = 0; j < 8; ++j) {
            const float f = bf2f(v[j]);   // cols >= 500 are zero
            s += f; q += f * f;
        }
        #pragma unroll
        for (int off = 32; off; off >>= 1) {
            s += __shfl_xor(s, off);
            q += __shfl_xor(q, off);
        }
        if (lane == 0) {
            const float mu = s * (1.0f / 500.0f);
            xstat[row] = make_float2(mu, rsqrtf(q - 500.0f * mu * mu));
        }
    }
}

// ---------------------------------------------------------------------------
// K4: G = Ab @ Xb^T (raw), epilogue C = (G - 500*muA*muX)*invA*invX.
// Tile 256m x 128j, 512 thr (8 waves 4x2, wave 64x64), swizzled LDS +
// reg prefetch. Grid 944 decoded XCD-grouped: jt=(d>>4)*8+(d&7) (<465),
// mt=(d>>3)&1 -> mt pairs of one jt share an XCD (Xb slice L2 reuse).
// ---------------------------------------------------------------------------
__global__ __launch_bounds__(512, 4) void k4_gemm2(const unsigned short* __restrict__ Ab,
                                                   const unsigned short* __restrict__ Xb,
                                                   const float2* __restrict__ astat,
                                                   const float2* __restrict__ xstat,
                                                   float* __restrict__ C) {
    const int d  = blockIdx.x;
    const int jt = (d >> 4) * 8 + (d & 7);
    if (jt >= 465) return;
    const int mt = (d >> 3) & 1;
    const int j0 = jt * 128;
    const int m0 = mt * 256;

    __shared__ unsigned short As[256 * 64];
    __shared__ unsigned short Bs[128 * 64];
    const int t = threadIdx.x, lane = t & 63, wid = t >> 6;
    const int wm = wid >> 1;   // 0..3
    const int wn = wid & 1;    // 0..1
    const int lg = lane >> 4, lr = lane & 15;

    f32x4 acc[4][4];
    #pragma unroll
    for (int i = 0; i < 4; ++i)
        #pragma unroll
        for (int j = 0; j < 4; ++j) {
            f32x4 z = {0.f, 0.f, 0.f, 0.f};
            acc[i][j] = z;
        }

    // staging: A rows ar=t>>1 (0..255), 32-k seg; B rows br=t>>2 (0..127), 16-k seg
    const int ar = t >> 1, aseg = t & 1;
    const int br = t >> 2, bseg = t & 3;
    const unsigned short* ag = Ab + (size_t)(m0 + ar) * T_PAD + aseg * 32;
    const unsigned short* bg = Xb + (size_t)(j0 + br) * T_PAD + bseg * 16;
    const int akey = ((ar >> 2) & 7) << 3;
    const int bkey = ((br >> 2) & 7) << 3;

    u16x8 ha[4], hb[2];
    auto load6 = [&](int k0) {
        #pragma unroll
        for (int q = 0; q < 4; ++q) ha[q] = *(const u16x8*)(ag + k0 + q * 8);
        #pragma unroll
        for (int q = 0; q < 2; ++q) hb[q] = *(const u16x8*)(bg + k0 + q * 8);
    };
    load6(0);

    for (int st = 0; st < 8; ++st) {
        #pragma unroll
        for (int q = 0; q < 4; ++q)
            *(u16x8*)&As[ar * 64 + ((aseg * 32 + q * 8) ^ akey)] = ha[q];
        #pragma unroll
        for (int q = 0; q < 2; ++q)
            *(u16x8*)&Bs[br * 64 + ((bseg * 16 + q * 8) ^ bkey)] = hb[q];
        __syncthreads();
        if (st < 7) load6((st + 1) * 64);
        #pragma unroll
        for (int h = 0; h < 2; ++h) {
            u16x8 bf4[4];
            #pragma unroll
            for (int nf = 0; nf < 4; ++nf) {
                const int n = wn * 64 + nf * 16 + lr;
                bf4[nf] = *(const u16x8*)&Bs[n * 64 + ((h * 32 + lg * 8) ^ (((n >> 2) & 7) << 3))];
            }
            #pragma unroll
            for (int mf = 0; mf < 4; ++mf) {
                const int m = wm * 64 + mf * 16 + lr;
                const u16x8 af = *(const u16x8*)&As[m * 64 + ((h * 32 + lg * 8) ^ (((m >> 2) & 7) << 3))];
                #pragma unroll
                for (int nf = 0; nf < 4; ++nf)
                    acc[mf][nf] = mfma16(af, bf4[nf], acc[mf][nf]);
            }
        }
        __syncthreads();
    }

    #pragma unroll
    for (int mf = 0; mf < 4; ++mf) {
        const int row = m0 + wm * 64 + mf * 16 + lg * 4;
        #pragma unroll
        for (int nf = 0; nf < 4; ++nf) {
            const int col = j0 + wn * 64 + nf * 16 + lr;
            if (col < N_LOCI) {
                const float2 xs = xstat[col];
                #pragma unroll
                for (int rr = 0; rr < 4; ++rr) {
                    if (row + rr < 2 * N_ENC) {
                        const float2 as = astat[row + rr];
                        C[(size_t)(row + rr) * N_LOCI + col] =
                            (acc[mf][nf][rr] - 500.0f * as.x * xs.x) * as.y * xs.y;
                    }
                }
            }
        }
    }
}

// ---------------------------------------------------------------------------
extern "C" void kernel_launch(void* const* d_in, const int* in_sizes, int n_in,
                              void* d_out, int out_size, void* d_ws, size_t ws_size,
                              hipStream_t stream) {
    const float* X  = (const float*)d_in[0];
    const float* WL = (const float*)d_in[1];
    const float* WR = (const float*)d_in[2];
    float* C = (float*)d_out;

    // workspace (total ~85.8 MB):
    //   Xb    u16 [59648][512]     : 61,079,552 B
    //   P16   u16 [116][200][512]  : 23,756,800 B
    //   Ab    u16 [512][512]       :    524,288 B
    //   astat f32x2 [512]          :      4,096 B
    //   xstat f32x2 [59648]        :    477,184 B
    char* w = (char*)d_ws;
    unsigned short* Xb  = (unsigned short*)w;  w += (size_t)J_PAD * T_PAD * 2;
    unsigned short* P16 = (unsigned short*)w;  w += (size_t)2 * G1_S * 200 * 512 * 2;
    unsigned short* Ab  = (unsigned short*)w;  w += (size_t)512 * 512 * 2;
    float2* astat = (float2*)w;                w += (size_t)512 * 8;
    float2* xstat = (float2*)w;

    k2_gemm1<<<dim3(8 * G1_S * 2 * 4), dim3(256), 0, stream>>>(X, WL, WR, P16, Xb);
    k3_astats<<<dim3(512), dim3(256), 0, stream>>>(P16, Ab, astat);
    k1_xstat<<<dim3(465), dim3(256), 0, stream>>>(Xb, xstat);
    k4_gemm2<<<dim3(944), dim3(512), 0, stream>>>(Ab, Xb, astat, xstat, C);
}

// Round 8
// 240.624 us; speedup vs baseline: 2.8661x; 2.8661x over previous
//
#include <hip/hip_runtime.h>

typedef __attribute__((ext_vector_type(8))) __bf16 bf16x8;
typedef __attribute__((ext_vector_type(8))) unsigned short u16x8;
typedef __attribute__((ext_vector_type(4))) unsigned short u16x4;
typedef __attribute__((ext_vector_type(4))) float f32x4;

#define N_LOCI   59412
#define T_DIM    500
#define T_PAD    512
#define N_ENC    200
#define KL       29696
#define KR       29716
#define J_PAD    59648
#define G1_S     58      // split-K chunks per compartment (58*512 >= K)

__device__ __forceinline__ unsigned short cvt1(float x) {
    __bf16 h = (__bf16)x;
    return __builtin_bit_cast(unsigned short, h);
}
__device__ __forceinline__ float bf2f(unsigned short h) {
    return __uint_as_float(((unsigned)h) << 16);
}
__device__ __forceinline__ f32x4 mfma16(u16x8 a, u16x8 b, f32x4 c) {
    return __builtin_amdgcn_mfma_f32_16x16x32_bf16(
        __builtin_bit_cast(bf16x8, a), __builtin_bit_cast(bf16x8, b), c, 0, 0, 0);
}

// ---------------------------------------------------------------------------
// K2: bf16 partials P16[g][200][512] of A = W_c @ X_slice (RAW, uncentered),
// plus (mt==0): raw-bf16 Xb[loci][512]. Tile M=128 x N=128, BK=64, 256 thr
// (4 waves 2x2, wave 64x64). NO min-wave launch bound (r7's (256,4) caused
// a 64-VGPR cap -> scratch spill -> 2.3 GB HBM traffic).
// Grid 928 g-major: d = g*8 + slot, slot = mt*4 + nt.
// ---------------------------------------------------------------------------
__global__ __launch_bounds__(256) void k2_gemm1(const float* __restrict__ X,
                                                const float* __restrict__ WL,
                                                const float* __restrict__ WR,
                                                unsigned short* __restrict__ P16,
                                                unsigned short* __restrict__ Xb) {
    const int d = blockIdx.x;
    const int g = d >> 3;          // 0..115
    const int slot = d & 7;
    const int mt = slot >> 2;      // 0..1
    const int nt = slot & 3;       // 0..3
    const int sc   = g >> 1;       // 0..57
    const int comp = g & 1;
    const int K      = comp ? KR : KL;
    const float* W   = comp ? WR : WL;
    const int xbase  = comp ? KL : 0;
    const int m0 = mt * 128;
    const int n0 = nt * 128;
    const bool emit = (mt == 0);

    __shared__ unsigned short As[128 * 64];
    __shared__ unsigned short Bs[128 * 64];

    const int t = threadIdx.x, lane = t & 63, wid = t >> 6;
    const int wm = wid >> 1, wn = wid & 1;
    const int lr = lane & 15, lg = lane >> 4;

    f32x4 acc[4][4];
    #pragma unroll
    for (int i = 0; i < 4; ++i)
        #pragma unroll
        for (int j = 0; j < 4; ++j) {
            f32x4 z = {0.f, 0.f, 0.f, 0.f};
            acc[i][j] = z;
        }

    const int nsteps = (comp && sc == G1_S - 1) ? 9 : 8;

    // A staging: row am (0..127), 32-k segment aseg
    const int am = t >> 1, aseg = t & 1;
    const int arow = (m0 + am < N_ENC) ? (m0 + am) : (N_ENC - 1);
    const float* wrow = W + (size_t)arow * K;
    const int akey = ((am >> 2) & 7) << 3;
    // B staging: k-quad kq (4 rows), col thread tc (8 cols)
    const int kq = t >> 4, tc = t & 15;

    u16x8 ha[4];
    unsigned short hv[4][8];

    auto load_tiles = [&](int st) {
        const int k0 = sc * 512 + st * 64;
        // ---- A: 32 k per thread ----
        {
            const int kb = k0 + aseg * 32;
            float av[32];
            if (kb + 31 < K) {
                #pragma unroll
                for (int f = 0; f < 8; ++f) {
                    const float4 v = *(const float4*)(wrow + kb + f * 4);
                    av[f * 4 + 0] = v.x; av[f * 4 + 1] = v.y;
                    av[f * 4 + 2] = v.z; av[f * 4 + 3] = v.w;
                }
            } else {
                #pragma unroll
                for (int j = 0; j < 32; ++j)
                    av[j] = (kb + j < K) ? wrow[kb + j] : 0.0f;
            }
            #pragma unroll
            for (int q = 0; q < 4; ++q) {
                u16x8 hh;
                #pragma unroll
                for (int j = 0; j < 8; ++j) hh[j] = cvt1(av[q * 8 + j]);
                ha[q] = hh;
            }
        }
        // ---- B: 4 rows x 8 cols per thread ----
        #pragma unroll
        for (int r = 0; r < 4; ++r) {
            const int krel = k0 + kq * 4 + r;
            const bool kok = krel < K;
            const float* xr = X + (size_t)(xbase + krel) * T_DIM;
            const int c = n0 + tc * 8;
            float xv[8];
            if (kok && c + 7 < T_DIM) {
                const float4 v0 = *(const float4*)(xr + c);
                const float4 v1 = *(const float4*)(xr + c + 4);
                xv[0] = v0.x; xv[1] = v0.y; xv[2] = v0.z; xv[3] = v0.w;
                xv[4] = v1.x; xv[5] = v1.y; xv[6] = v1.z; xv[7] = v1.w;
            } else {
                #pragma unroll
                for (int j = 0; j < 8; ++j)
                    xv[j] = (kok && c + j < T_DIM) ? xr[c + j] : 0.0f;
            }
            #pragma unroll
            for (int j = 0; j < 8; ++j) hv[r][j] = cvt1(xv[j]);
        }
    };

    auto write_stage = [&](int st) {
        #pragma unroll
        for (int q = 0; q < 4; ++q)
            *(u16x8*)&As[am * 64 + ((aseg * 32 + q * 8) ^ akey)] = ha[q];
        #pragma unroll
        for (int j = 0; j < 8; ++j) {
            const int nl = tc * 8 + j;
            const int key = (((nl >> 2) ^ (nl >> 5)) & 7) << 3;
            u16x4 w4 = { hv[0][j], hv[1][j], hv[2][j], hv[3][j] };
            *(u16x4*)&Bs[nl * 64 + ((kq * 4) ^ key)] = w4;
        }
        if (emit) {
            const int k0 = sc * 512 + st * 64;
            #pragma unroll
            for (int r = 0; r < 4; ++r) {
                const int krel = k0 + kq * 4 + r;
                if (krel < K) {
                    u16x8 hh;
                    #pragma unroll
                    for (int j = 0; j < 8; ++j) hh[j] = hv[r][j];
                    *(u16x8*)&Xb[(size_t)(xbase + krel) * T_PAD + n0 + tc * 8] = hh;
                }
            }
        }
    };

    load_tiles(0);
    for (int st = 0; st < nsteps; ++st) {
        write_stage(st);
        __syncthreads();
        if (st + 1 < nsteps) load_tiles(st + 1);   // reg prefetch
        #pragma unroll
        for (int h = 0; h < 2; ++h) {
            u16x8 af[4], bf[4];
            #pragma unroll
            for (int mf = 0; mf < 4; ++mf) {
                const int m = wm * 64 + mf * 16 + lr;
                af[mf] = *(const u16x8*)&As[m * 64 + ((h * 32 + lg * 8) ^ (((m >> 2) & 7) << 3))];
            }
            #pragma unroll
            for (int nf = 0; nf < 4; ++nf) {
                const int nl = wn * 64 + nf * 16 + lr;
                const int key = (((nl >> 2) ^ (nl >> 5)) & 7) << 3;
                bf[nf] = *(const u16x8*)&Bs[nl * 64 + ((h * 32 + lg * 8) ^ key)];
            }
            #pragma unroll
            for (int mf = 0; mf < 4; ++mf)
                #pragma unroll
                for (int nf = 0; nf < 4; ++nf)
                    acc[mf][nf] = mfma16(af[mf], bf[nf], acc[mf][nf]);
        }
        __syncthreads();
    }

    unsigned short* Pb = P16 + (size_t)g * (200 * 512);
    #pragma unroll
    for (int mf = 0; mf < 4; ++mf)
        #pragma unroll
        for (int rr = 0; rr < 4; ++rr) {
            const int m = m0 + wm * 64 + mf * 16 + lg * 4 + rr;
            if (m < N_ENC) {
                #pragma unroll
                for (int nf = 0; nf < 4; ++nf) {
                    const int n = n0 + wn * 64 + nf * 16 + lr;
                    Pb[(size_t)m * 512 + n] = cvt1(acc[mf][nf][rr]);
                }
            }
        }
}

// ---------------------------------------------------------------------------
// K3: sum bf16 split-K partials (slice = s2*2 + comp) -> raw A row;
// store RAW bf16 Ab [512][512] (pad zero) + astat=(mu, 1/||Ac||).
// ---------------------------------------------------------------------------
__global__ __launch_bounds__(256) void k3_astats(const unsigned short* __restrict__ P16,
                                                 unsigned short* __restrict__ Ab,
                                                 float2* __restrict__ astat) {
    const int r = blockIdx.x;   // 0..511
    const int t = threadIdx.x;  // 0..255
    unsigned short* out = Ab + (size_t)r * T_PAD;
    if (r >= 2 * N_ENC) {
        out[t] = 0; out[t + 256] = 0;
        if (t == 0) astat[r] = make_float2(0.0f, 0.0f);
        return;
    }
    const int comp = (r >= N_ENC) ? 1 : 0;
    const int m = r - comp * N_ENC;
    float a1 = 0.0f, a2 = 0.0f;
    for (int s2 = 0; s2 < G1_S; ++s2) {
        const unsigned short* Pb = P16 + ((size_t)(s2 * 2 + comp) * 200 + m) * 512;
        a1 += bf2f(Pb[t]);
        a2 += bf2f(Pb[t + 256]);
    }
    const bool v2ok = (t + 256) < T_DIM;
    const float b2 = v2ok ? a2 : 0.0f;
    float s = a1 + b2;
    float q = a1 * a1 + b2 * b2;
    #pragma unroll
    for (int off = 32; off; off >>= 1) {
        s += __shfl_xor(s, off);
        q += __shfl_xor(q, off);
    }
    __shared__ float ls[4], lq[4];
    if ((t & 63) == 0) { ls[t >> 6] = s; lq[t >> 6] = q; }
    __syncthreads();
    const float S = ls[0] + ls[1] + ls[2] + ls[3];
    const float Q = lq[0] + lq[1] + lq[2] + lq[3];
    const float mean = S * (1.0f / 500.0f);
    const float iv   = rsqrtf(Q - 500.0f * mean * mean);
    out[t] = cvt1(a1);
    out[t + 256] = v2ok ? cvt1(a2) : (unsigned short)0;
    if (t == 0) astat[r] = make_float2(mean, iv);
}

// ---------------------------------------------------------------------------
// K1x: per-locus stats from raw bf16 Xb: xstat = (mu, 1/||xc||).
// 465 blocks x 4 waves; each wave streams 32 consecutive rows.
// ---------------------------------------------------------------------------
__global__ __launch_bounds__(256) void k1_xstat(const unsigned short* __restrict__ Xb,
                                                float2* __restrict__ xstat) {
    const int w    = threadIdx.x >> 6;
    const int lane = threadIdx.x & 63;
    const int rbase = blockIdx.x * 128 + w * 32;
    for (int i = 0; i < 32; ++i) {
        const int row = rbase + i;
        if (row >= N_LOCI) return;   // uniform within wave
        const u16x8 v = *(const u16x8*)(Xb + (size_t)row * T_PAD + lane * 8);
        float s = 0.0f, q = 0.0f;
        #pragma unroll
        for (int j = 0; j < 8; ++j) {
            const float f = bf2f(v[j]);   // cols >= 500 are zero
            s += f; q += f * f;
        }
        #pragma unroll
        for (int off = 32; off; off >>= 1) {
            s += __shfl_xor(s, off);
            q += __shfl_xor(q, off);
        }
        if (lane == 0) {
            const float mu = s * (1.0f / 500.0f);
            xstat[row] = make_float2(mu, rsqrtf(q - 500.0f * mu * mu));
        }
    }
}

// ---------------------------------------------------------------------------
// K4: G = Ab @ Xb^T (raw), epilogue C = (G - 500*muA*muX)*invA*invX.
// r6-proven: tile 128m x 128j, 256 thr, swizzled LDS + reg prefetch.
// Grid 1888 decoded XCD-grouped: jt=(d>>5)*8+(d&7), mt=(d>>3)&3.
// ---------------------------------------------------------------------------
__global__ __launch_bounds__(256, 3) void k4_gemm2(const unsigned short* __restrict__ Ab,
                                                   const unsigned short* __restrict__ Xb,
                                                   const float2* __restrict__ astat,
                                                   const float2* __restrict__ xstat,
                                                   float* __restrict__ C) {
    const int d  = blockIdx.x;
    const int jt = (d >> 5) * 8 + (d & 7);
    if (jt >= 465) return;
    const int mt = (d >> 3) & 3;
    const int j0 = jt * 128;
    const int m0 = mt * 128;

    __shared__ unsigned short As[128 * 64];
    __shared__ unsigned short Bs[128 * 64];
    const int t = threadIdx.x, lane = t & 63;
    const int wm = (t >> 6) >> 1, wnn = (t >> 6) & 1;
    const int lg = lane >> 4, lr = lane & 15;

    f32x4 acc[4][4];
    #pragma unroll
    for (int i = 0; i < 4; ++i)
        #pragma unroll
        for (int j = 0; j < 4; ++j) {
            f32x4 z = {0.f, 0.f, 0.f, 0.f};
            acc[i][j] = z;
        }

    const int ar = t >> 1, aseg = t & 1;
    const unsigned short* ag = Ab + (size_t)(m0 + ar) * T_PAD + aseg * 32;
    const unsigned short* bg = Xb + (size_t)(j0 + ar) * T_PAD + aseg * 32;
    const int akey = ((ar >> 2) & 7) << 3;

    u16x8 ha[4], hb[4];
    auto load4 = [&](int k0, u16x8 (&la)[4], u16x8 (&lb)[4]) {
        #pragma unroll
        for (int q = 0; q < 4; ++q) la[q] = *(const u16x8*)(ag + k0 + q * 8);
        #pragma unroll
        for (int q = 0; q < 4; ++q) lb[q] = *(const u16x8*)(bg + k0 + q * 8);
    };
    load4(0, ha, hb);

    for (int st = 0; st < 8; ++st) {
        #pragma unroll
        for (int q = 0; q < 4; ++q) {
            const int off = ar * 64 + ((aseg * 32 + q * 8) ^ akey);
            *(u16x8*)&As[off] = ha[q];
            *(u16x8*)&Bs[off] = hb[q];
        }
        __syncthreads();
        u16x8 na[4], nb[4];
        const bool more = st < 7;
        if (more) load4((st + 1) * 64, na, nb);
        #pragma unroll
        for (int h = 0; h < 2; ++h) {
            u16x8 bf4[4];
            #pragma unroll
            for (int nf = 0; nf < 4; ++nf) {
                const int n = wnn * 64 + nf * 16 + lr;
                bf4[nf] = *(const u16x8*)&Bs[n * 64 + ((h * 32 + lg * 8) ^ (((n >> 2) & 7) << 3))];
            }
            #pragma unroll
            for (int mf = 0; mf < 4; ++mf) {
                const int m = wm * 64 + mf * 16 + lr;
                const u16x8 af = *(const u16x8*)&As[m * 64 + ((h * 32 + lg * 8) ^ (((m >> 2) & 7) << 3))];
                #pragma unroll
                for (int nf = 0; nf < 4; ++nf)
                    acc[mf][nf] = mfma16(af, bf4[nf], acc[mf][nf]);
            }
        }
        __syncthreads();
        if (more) {
            #pragma unroll
            for (int q = 0; q < 4; ++q) { ha[q] = na[q]; hb[q] = nb[q]; }
        }
    }

    #pragma unroll
    for (int mf = 0; mf < 4; ++mf) {
        const int row = m0 + wm * 64 + mf * 16 + lg * 4;
        #pragma unroll
        for (int nf = 0; nf < 4; ++nf) {
            const int col = j0 + wnn * 64 + nf * 16 + lr;
            if (col < N_LOCI) {
                const float2 xs = xstat[col];
                #pragma unroll
                for (int rr = 0; rr < 4; ++rr) {
                    if (row + rr < 2 * N_ENC) {
                        const float2 as = astat[row + rr];
                        C[(size_t)(row + rr) * N_LOCI + col] =
                            (acc[mf][nf][rr] - 500.0f * as.x * xs.x) * as.y * xs.y;
                    }
                }
            }
        }
    }
}

// ---------------------------------------------------------------------------
extern "C" void kernel_launch(void* const* d_in, const int* in_sizes, int n_in,
                              void* d_out, int out_size, void* d_ws, size_t ws_size,
                              hipStream_t stream) {
    const float* X  = (const float*)d_in[0];
    const float* WL = (const float*)d_in[1];
    const float* WR = (const float*)d_in[2];
    float* C = (float*)d_out;

    // workspace (total ~85.8 MB):
    //   Xb    u16 [59648][512]     : 61,079,552 B
    //   P16   u16 [116][200][512]  : 23,756,800 B
    //   Ab    u16 [512][512]       :    524,288 B
    //   astat f32x2 [512]          :      4,096 B
    //   xstat f32x2 [59648]        :    477,184 B
    char* w = (char*)d_ws;
    unsigned short* Xb  = (unsigned short*)w;  w += (size_t)J_PAD * T_PAD * 2;
    unsigned short* P16 = (unsigned short*)w;  w += (size_t)2 * G1_S * 200 * 512 * 2;
    unsigned short* Ab  = (unsigned short*)w;  w += (size_t)512 * 512 * 2;
    float2* astat = (float2*)w;                w += (size_t)512 * 8;
    float2* xstat = (float2*)w;

    k2_gemm1<<<dim3(8 * G1_S * 2), dim3(256), 0, stream>>>(X, WL, WR, P16, Xb);
    k3_astats<<<dim3(512), dim3(256), 0, stream>>>(P16, Ab, astat);
    k1_xstat<<<dim3(465), dim3(256), 0, stream>>>(Xb, xstat);
    k4_gemm2<<<dim3(1888), dim3(256), 0, stream>>>(Ab, Xb, astat, xstat, C);
}

// Round 9
// 202.199 us; speedup vs baseline: 3.4107x; 1.1900x over previous
//
#include <hip/hip_runtime.h>

typedef __attribute__((ext_vector_type(8))) __bf16 bf16x8;
typedef __attribute__((ext_vector_type(8))) unsigned short u16x8;
typedef __attribute__((ext_vector_type(4))) unsigned short u16x4;
typedef __attribute__((ext_vector_type(4))) float f32x4;

#define N_LOCI   59412
#define T_DIM    500
#define T_PAD    512
#define N_ENC    200
#define KL       29696
#define KR       29716
#define J_PAD    59648
#define G1_S     58      // split-K chunks per compartment (58*512 >= K)

__device__ __forceinline__ unsigned short cvt1(float x) {
    __bf16 h = (__bf16)x;
    return __builtin_bit_cast(unsigned short, h);
}
__device__ __forceinline__ float bf2f(unsigned short h) {
    return __uint_as_float(((unsigned)h) << 16);
}
__device__ __forceinline__ f32x4 mfma16(u16x8 a, u16x8 b, f32x4 c) {
    return __builtin_amdgcn_mfma_f32_16x16x32_bf16(
        __builtin_bit_cast(bf16x8, a), __builtin_bit_cast(bf16x8, b), c, 0, 0, 0);
}

// ---------------------------------------------------------------------------
// K2: bf16 partials P16[g][200][512] of A = W_c @ X_slice (RAW), plus
// (mt==0): raw-bf16 Xb[loci][512]. Tile M=128 x N=256, BK=64, 512 thr
// (8 waves 2m x 4n, wave 64x64). Swizzles: A key (row&7)<<3,
// B key ((nl^(nl>>3))&7)<<3 (write/read consistent, verified bijective).
// Slot-major grid d = slot*128 + g (slot = mt*2+nt, 4 slots): all partners
// of chunk g share d%8 -> same XCD L2. 512 blocks = 2/CU, full residency.
// ---------------------------------------------------------------------------
__global__ __launch_bounds__(512) void k2_gemm1(const float* __restrict__ X,
                                                const float* __restrict__ WL,
                                                const float* __restrict__ WR,
                                                unsigned short* __restrict__ P16,
                                                unsigned short* __restrict__ Xb) {
    const int d = blockIdx.x;
    const int g = d & 127;
    if (g >= 2 * G1_S) return;
    const int slot = d >> 7;       // 0..3
    const int mt = slot >> 1;      // 0..1
    const int nt = slot & 1;       // 0..1
    const int sc   = g >> 1;       // 0..57
    const int comp = g & 1;
    const int K      = comp ? KR : KL;
    const float* W   = comp ? WR : WL;
    const int xbase  = comp ? KL : 0;
    const int m0 = mt * 128;
    const int n0 = nt * 256;
    const bool emit = (mt == 0);

    __shared__ unsigned short As[128 * 64];   // 16 KB
    __shared__ unsigned short Bs[256 * 64];   // 32 KB

    const int t = threadIdx.x, lane = t & 63, wid = t >> 6;
    const int wm = wid >> 2, wn = wid & 3;
    const int lr = lane & 15, lg = lane >> 4;

    f32x4 acc[4][4];
    #pragma unroll
    for (int i = 0; i < 4; ++i)
        #pragma unroll
        for (int j = 0; j < 4; ++j) {
            f32x4 z = {0.f, 0.f, 0.f, 0.f};
            acc[i][j] = z;
        }

    const int nsteps = (comp && sc == G1_S - 1) ? 9 : 8;

    // A staging: row am (0..127), 16-k segment aseg (0..3)
    const int am = t >> 2, aseg = t & 3;
    const int arow = (m0 + am < N_ENC) ? (m0 + am) : (N_ENC - 1);
    const float* wrow = W + (size_t)arow * K;
    const int akey = (am & 7) << 3;
    // B staging: k-quad kq (0..15 -> 4 rows), col thread tc (0..31 -> 8 cols)
    const int kq = t >> 5, tc = t & 31;

    u16x8 ha[2];
    unsigned short hv[4][8];

    auto load_tiles = [&](int st) {
        const int k0 = sc * 512 + st * 64;
        // ---- A: 16 k per thread ----
        {
            const int kb = k0 + aseg * 16;
            float av[16];
            if (kb + 15 < K) {
                #pragma unroll
                for (int f = 0; f < 4; ++f) {
                    const float4 v = *(const float4*)(wrow + kb + f * 4);
                    av[f * 4 + 0] = v.x; av[f * 4 + 1] = v.y;
                    av[f * 4 + 2] = v.z; av[f * 4 + 3] = v.w;
                }
            } else {
                #pragma unroll
                for (int j = 0; j < 16; ++j)
                    av[j] = (kb + j < K) ? wrow[kb + j] : 0.0f;
            }
            #pragma unroll
            for (int h2 = 0; h2 < 2; ++h2) {
                u16x8 hh;
                #pragma unroll
                for (int j = 0; j < 8; ++j) hh[j] = cvt1(av[h2 * 8 + j]);
                ha[h2] = hh;
            }
        }
        // ---- B: 4 rows x 8 cols per thread ----
        #pragma unroll
        for (int r = 0; r < 4; ++r) {
            const int krel = k0 + kq * 4 + r;
            const bool kok = krel < K;
            const float* xr = X + (size_t)(xbase + krel) * T_DIM;
            const int c = n0 + tc * 8;
            float xv[8];
            if (kok && c + 7 < T_DIM) {
                const float4 v0 = *(const float4*)(xr + c);
                const float4 v1 = *(const float4*)(xr + c + 4);
                xv[0] = v0.x; xv[1] = v0.y; xv[2] = v0.z; xv[3] = v0.w;
                xv[4] = v1.x; xv[5] = v1.y; xv[6] = v1.z; xv[7] = v1.w;
            } else {
                #pragma unroll
                for (int j = 0; j < 8; ++j)
                    xv[j] = (kok && c + j < T_DIM) ? xr[c + j] : 0.0f;
            }
            #pragma unroll
            for (int j = 0; j < 8; ++j) hv[r][j] = cvt1(xv[j]);
        }
    };

    auto write_stage = [&](int st) {
        *(u16x8*)&As[am * 64 + ((aseg * 16)     ^ akey)] = ha[0];
        *(u16x8*)&As[am * 64 + ((aseg * 16 + 8) ^ akey)] = ha[1];
        #pragma unroll
        for (int j = 0; j < 8; ++j) {
            const int nl = tc * 8 + j;
            const int key = ((nl ^ (nl >> 3)) & 7) << 3;
            u16x4 w4 = { hv[0][j], hv[1][j], hv[2][j], hv[3][j] };
            *(u16x4*)&Bs[nl * 64 + ((kq * 4) ^ key)] = w4;
        }
        if (emit) {
            const int k0 = sc * 512 + st * 64;
            #pragma unroll
            for (int r = 0; r < 4; ++r) {
                const int krel = k0 + kq * 4 + r;
                if (krel < K) {
                    u16x8 hh;
                    #pragma unroll
                    for (int j = 0; j < 8; ++j) hh[j] = hv[r][j];
                    *(u16x8*)&Xb[(size_t)(xbase + krel) * T_PAD + n0 + tc * 8] = hh;
                }
            }
        }
    };

    load_tiles(0);
    for (int st = 0; st < nsteps; ++st) {
        write_stage(st);
        __syncthreads();
        if (st + 1 < nsteps) load_tiles(st + 1);   // loads in flight during MFMA
        #pragma unroll
        for (int h = 0; h < 2; ++h) {
            u16x8 af[4], bf[4];
            #pragma unroll
            for (int mf = 0; mf < 4; ++mf) {
                const int m = wm * 64 + mf * 16 + lr;
                af[mf] = *(const u16x8*)&As[m * 64 + ((h * 32 + lg * 8) ^ ((m & 7) << 3))];
            }
            #pragma unroll
            for (int nf = 0; nf < 4; ++nf) {
                const int nl = wn * 64 + nf * 16 + lr;
                const int key = ((nl ^ (nl >> 3)) & 7) << 3;
                bf[nf] = *(const u16x8*)&Bs[nl * 64 + ((h * 32 + lg * 8) ^ key)];
            }
            #pragma unroll
            for (int mf = 0; mf < 4; ++mf)
                #pragma unroll
                for (int nf = 0; nf < 4; ++nf)
                    acc[mf][nf] = mfma16(af[mf], bf[nf], acc[mf][nf]);
        }
        __syncthreads();
    }

    unsigned short* Pb = P16 + (size_t)g * (200 * 512);
    #pragma unroll
    for (int mf = 0; mf < 4; ++mf)
        #pragma unroll
        for (int rr = 0; rr < 4; ++rr) {
            const int m = m0 + wm * 64 + mf * 16 + lg * 4 + rr;
            if (m < N_ENC) {
                #pragma unroll
                for (int nf = 0; nf < 4; ++nf) {
                    const int n = n0 + wn * 64 + nf * 16 + lr;
                    Pb[(size_t)m * 512 + n] = cvt1(acc[mf][nf][rr]);
                }
            }
        }
}

// ---------------------------------------------------------------------------
// K3: sum bf16 split-K partials (slice = s2*2 + comp) -> raw A row;
// store RAW bf16 Ab [512][512] (pad zero) + astat=(mu, 1/||Ac||).
// ---------------------------------------------------------------------------
__global__ __launch_bounds__(256) void k3_astats(const unsigned short* __restrict__ P16,
                                                 unsigned short* __restrict__ Ab,
                                                 float2* __restrict__ astat) {
    const int r = blockIdx.x;   // 0..511
    const int t = threadIdx.x;  // 0..255
    unsigned short* out = Ab + (size_t)r * T_PAD;
    if (r >= 2 * N_ENC) {
        out[t] = 0; out[t + 256] = 0;
        if (t == 0) astat[r] = make_float2(0.0f, 0.0f);
        return;
    }
    const int comp = (r >= N_ENC) ? 1 : 0;
    const int m = r - comp * N_ENC;
    float a1 = 0.0f, a2 = 0.0f;
    for (int s2 = 0; s2 < G1_S; ++s2) {
        const unsigned short* Pb = P16 + ((size_t)(s2 * 2 + comp) * 200 + m) * 512;
        a1 += bf2f(Pb[t]);
        a2 += bf2f(Pb[t + 256]);
    }
    const bool v2ok = (t + 256) < T_DIM;
    const float b2 = v2ok ? a2 : 0.0f;
    float s = a1 + b2;
    float q = a1 * a1 + b2 * b2;
    #pragma unroll
    for (int off = 32; off; off >>= 1) {
        s += __shfl_xor(s, off);
        q += __shfl_xor(q, off);
    }
    __shared__ float ls[4], lq[4];
    if ((t & 63) == 0) { ls[t >> 6] = s; lq[t >> 6] = q; }
    __syncthreads();
    const float S = ls[0] + ls[1] + ls[2] + ls[3];
    const float Q = lq[0] + lq[1] + lq[2] + lq[3];
    const float mean = S * (1.0f / 500.0f);
    const float iv   = rsqrtf(Q - 500.0f * mean * mean);
    out[t] = cvt1(a1);
    out[t + 256] = v2ok ? cvt1(a2) : (unsigned short)0;
    if (t == 0) astat[r] = make_float2(mean, iv);
}

// ---------------------------------------------------------------------------
// K1x: per-locus stats from raw bf16 Xb: xstat = (mu, 1/||xc||).
// 465 blocks x 4 waves; each wave streams 32 consecutive rows.
// ---------------------------------------------------------------------------
__global__ __launch_bounds__(256) void k1_xstat(const unsigned short* __restrict__ Xb,
                                                float2* __restrict__ xstat) {
    const int w    = threadIdx.x >> 6;
    const int lane = threadIdx.x & 63;
    const int rbase = blockIdx.x * 128 + w * 32;
    for (int i = 0; i < 32; ++i) {
        const int row = rbase + i;
        if (row >= N_LOCI) return;   // uniform within wave
        const u16x8 v = *(const u16x8*)(Xb + (size_t)row * T_PAD + lane * 8);
        float s = 0.0f, q = 0.0f;
        #pragma unroll
        for (int j = 0; j < 8; ++j) {
            const float f = bf2f(v[j]);   // cols >= 500 are zero
            s += f; q += f * f;
        }
        #pragma unroll
        for (int off = 32; off; off >>= 1) {
            s += __shfl_xor(s, off);
            q += __shfl_xor(q, off);
        }
        if (lane == 0) {
            const float mu = s * (1.0f / 500.0f);
            xstat[row] = make_float2(mu, rsqrtf(q - 500.0f * mu * mu));
        }
    }
}

// ---------------------------------------------------------------------------
// K4: G = Ab @ Xb^T (raw), epilogue C = (G - 500*muA*muX)*invA*invX.
// Tile 256m x 128j, 512 thr (8 waves 4m x 2n, wave 64x64), swizzled LDS
// ((row&7)<<3) + reg prefetch. NO min-wave bound (r7 spill lesson).
// Grid 944 decoded XCD-grouped: jt=(d>>4)*8+(d&7) (<465), mt=(d>>3)&1 ->
// the two mt partners of a jt share an XCD (Xb tile L2 reuse).
// ---------------------------------------------------------------------------
__global__ __launch_bounds__(512) void k4_gemm2(const unsigned short* __restrict__ Ab,
                                                const unsigned short* __restrict__ Xb,
                                                const float2* __restrict__ astat,
                                                const float2* __restrict__ xstat,
                                                float* __restrict__ C) {
    const int d  = blockIdx.x;
    const int jt = (d >> 4) * 8 + (d & 7);
    if (jt >= 465) return;
    const int mt = (d >> 3) & 1;
    const int j0 = jt * 128;
    const int m0 = mt * 256;

    __shared__ unsigned short As[256 * 64];   // 32 KB
    __shared__ unsigned short Bs[128 * 64];   // 16 KB
    const int t = threadIdx.x, lane = t & 63, wid = t >> 6;
    const int wm = wid >> 1;   // 0..3
    const int wn = wid & 1;    // 0..1
    const int lg = lane >> 4, lr = lane & 15;

    f32x4 acc[4][4];
    #pragma unroll
    for (int i = 0; i < 4; ++i)
        #pragma unroll
        for (int j = 0; j < 4; ++j) {
            f32x4 z = {0.f, 0.f, 0.f, 0.f};
            acc[i][j] = z;
        }

    // staging: A rows ar (0..255) 32-k seg; B rows br (0..127) 16-k seg
    const int ar = t >> 1, aseg = t & 1;
    const int br = t >> 2, bseg = t & 3;
    const unsigned short* ag = Ab + (size_t)(m0 + ar) * T_PAD + aseg * 32;
    const unsigned short* bg = Xb + (size_t)(j0 + br) * T_PAD + bseg * 16;
    const int akey = (ar & 7) << 3;
    const int bkey = (br & 7) << 3;

    u16x8 ha[4], hb[2];
    auto load6 = [&](int k0, u16x8 (&la)[4], u16x8 (&lb)[2]) {
        #pragma unroll
        for (int q = 0; q < 4; ++q) la[q] = *(const u16x8*)(ag + k0 + q * 8);
        #pragma unroll
        for (int q = 0; q < 2; ++q) lb[q] = *(const u16x8*)(bg + k0 + q * 8);
    };
    load6(0, ha, hb);

    for (int st = 0; st < 8; ++st) {
        #pragma unroll
        for (int q = 0; q < 4; ++q)
            *(u16x8*)&As[ar * 64 + ((aseg * 32 + q * 8) ^ akey)] = ha[q];
        #pragma unroll
        for (int q = 0; q < 2; ++q)
            *(u16x8*)&Bs[br * 64 + ((bseg * 16 + q * 8) ^ bkey)] = hb[q];
        __syncthreads();
        u16x8 na[4]; u16x8 nb[2];
        const bool more = st < 7;
        if (more) load6((st + 1) * 64, na, nb);
        #pragma unroll
        for (int h = 0; h < 2; ++h) {
            u16x8 bf4[4];
            #pragma unroll
            for (int nf = 0; nf < 4; ++nf) {
                const int n = wn * 64 + nf * 16 + lr;
                bf4[nf] = *(const u16x8*)&Bs[n * 64 + ((h * 32 + lg * 8) ^ ((n & 7) << 3))];
            }
            #pragma unroll
            for (int mf = 0; mf < 4; ++mf) {
                const int m = wm * 64 + mf * 16 + lr;
                const u16x8 af = *(const u16x8*)&As[m * 64 + ((h * 32 + lg * 8) ^ ((m & 7) << 3))];
                #pragma unroll
                for (int nf = 0; nf < 4; ++nf)
                    acc[mf][nf] = mfma16(af, bf4[nf], acc[mf][nf]);
            }
        }
        __syncthreads();
        if (more) {
            #pragma unroll
            for (int q = 0; q < 4; ++q) ha[q] = na[q];
            #pragma unroll
            for (int q = 0; q < 2; ++q) hb[q] = nb[q];
        }
    }

    #pragma unroll
    for (int mf = 0; mf < 4; ++mf) {
        const int row = m0 + wm * 64 + mf * 16 + lg * 4;
        #pragma unroll
        for (int nf = 0; nf < 4; ++nf) {
            const int col = j0 + wn * 64 + nf * 16 + lr;
            if (col < N_LOCI) {
                const float2 xs = xstat[col];
                #pragma unroll
                for (int rr = 0; rr < 4; ++rr) {
                    if (row + rr < 2 * N_ENC) {
                        const float2 as = astat[row + rr];
                        C[(size_t)(row + rr) * N_LOCI + col] =
                            (acc[mf][nf][rr] - 500.0f * as.x * xs.x) * as.y * xs.y;
                    }
                }
            }
        }
    }
}

// ---------------------------------------------------------------------------
extern "C" void kernel_launch(void* const* d_in, const int* in_sizes, int n_in,
                              void* d_out, int out_size, void* d_ws, size_t ws_size,
                              hipStream_t stream) {
    const float* X  = (const float*)d_in[0];
    const float* WL = (const float*)d_in[1];
    const float* WR = (const float*)d_in[2];
    float* C = (float*)d_out;

    // workspace (total ~85.8 MB):
    //   Xb    u16 [59648][512]     : 61,079,552 B
    //   P16   u16 [116][200][512]  : 23,756,800 B
    //   Ab    u16 [512][512]       :    524,288 B
    //   astat f32x2 [512]          :      4,096 B
    //   xstat f32x2 [59648]        :    477,184 B
    char* w = (char*)d_ws;
    unsigned short* Xb  = (unsigned short*)w;  w += (size_t)J_PAD * T_PAD * 2;
    unsigned short* P16 = (unsigned short*)w;  w += (size_t)2 * G1_S * 200 * 512 * 2;
    unsigned short* Ab  = (unsigned short*)w;  w += (size_t)512 * 512 * 2;
    float2* astat = (float2*)w;                w += (size_t)512 * 8;
    float2* xstat = (float2*)w;

    k2_gemm1<<<dim3(512), dim3(512), 0, stream>>>(X, WL, WR, P16, Xb);
    k3_astats<<<dim3(512), dim3(256), 0, stream>>>(P16, Ab, astat);
    k1_xstat<<<dim3(465), dim3(256), 0, stream>>>(Xb, xstat);
    k4_gemm2<<<dim3(944), dim3(512), 0, stream>>>(Ab, Xb, astat, xstat, C);
}

// Round 10
// 169.335 us; speedup vs baseline: 4.0727x; 1.1941x over previous
//
#include <hip/hip_runtime.h>

typedef __attribute__((ext_vector_type(8))) __bf16 bf16x8;
typedef __attribute__((ext_vector_type(8))) unsigned short u16x8;
typedef __attribute__((ext_vector_type(4))) unsigned short u16x4;
typedef __attribute__((ext_vector_type(4))) float f32x4;

#define N_LOCI   59412
#define T_DIM    500
#define T_PAD    512
#define N_ENC    200
#define KL       29696
#define KR       29716
#define J_PAD    59648
#define G1_S     58      // split-K chunks per compartment (58*512 >= K)

__device__ __forceinline__ unsigned short cvt1(float x) {
    __bf16 h = (__bf16)x;
    return __builtin_bit_cast(unsigned short, h);
}
__device__ __forceinline__ float bf2f(unsigned short h) {
    return __uint_as_float(((unsigned)h) << 16);
}
__device__ __forceinline__ f32x4 mfma16(u16x8 a, u16x8 b, f32x4 c) {
    return __builtin_amdgcn_mfma_f32_16x16x32_bf16(
        __builtin_bit_cast(bf16x8, a), __builtin_bit_cast(bf16x8, b), c, 0, 0, 0);
}

// ---------------------------------------------------------------------------
// K0: stream X f32 -> raw bf16 Xb [J_PAD][512] (rows>=N_LOCI and cols>=500
// zeroed) + xstat=(mu, 1/||xc||). One wave per row, 4 rows per wave.
// ---------------------------------------------------------------------------
__global__ __launch_bounds__(256) void k0_xraw(const float* __restrict__ X,
                                               unsigned short* __restrict__ Xb,
                                               float2* __restrict__ xstat) {
    const int w    = threadIdx.x >> 6;
    const int lane = threadIdx.x & 63;
    const int base = blockIdx.x * 16 + w * 4;
    for (int i = 0; i < 4; ++i) {
        const int row = base + i;
        unsigned short* out = Xb + (size_t)row * T_PAD;
        if (row >= N_LOCI) {
            u16x4 z = {0, 0, 0, 0};
            *(u16x4*)(out + lane * 4) = z;
            *(u16x4*)(out + (lane + 64) * 4) = z;
            if (lane == 0) xstat[row] = make_float2(0.0f, 0.0f);
            continue;
        }
        const float4* xr = (const float4*)(X + (size_t)row * T_DIM);
        float4 v1 = xr[lane];
        float4 v2 = make_float4(0.f, 0.f, 0.f, 0.f);
        const bool has2 = (lane + 64) < 125;
        if (has2) v2 = xr[lane + 64];
        float s = v1.x + v1.y + v1.z + v1.w + v2.x + v2.y + v2.z + v2.w;
        float q = v1.x * v1.x + v1.y * v1.y + v1.z * v1.z + v1.w * v1.w
                + v2.x * v2.x + v2.y * v2.y + v2.z * v2.z + v2.w * v2.w;
        #pragma unroll
        for (int off = 32; off; off >>= 1) {
            s += __shfl_xor(s, off);
            q += __shfl_xor(q, off);
        }
        u16x4 w1, w2 = {0, 0, 0, 0};
        w1[0] = cvt1(v1.x); w1[1] = cvt1(v1.y); w1[2] = cvt1(v1.z); w1[3] = cvt1(v1.w);
        if (has2) {
            w2[0] = cvt1(v2.x); w2[1] = cvt1(v2.y); w2[2] = cvt1(v2.z); w2[3] = cvt1(v2.w);
        }
        *(u16x4*)(out + lane * 4) = w1;
        *(u16x4*)(out + (lane + 64) * 4) = w2;
        if (lane == 0) {
            const float mu = s * (1.0f / 500.0f);
            xstat[row] = make_float2(mu, rsqrtf(q - 500.0f * mu * mu));
        }
    }
}

// ---------------------------------------------------------------------------
// K2: bf16 partials P16[g][200][512] of A = W_c @ X_slice (RAW). B side now
// reads bf16 Xb (half the bytes, no cvt). Tile M=128 x N=128, BK=64, 256 thr
// (4 waves 2x2, wave 64x64), 32 KB LDS (~3.6 blocks/CU at grid 1024).
// Swizzles (verified write/read-consistent): A key (row&7)<<3,
// B key ((nl^(nl>>3))&7)<<3. Slot-major grid d = slot*128 + g: all 8 slots
// (mt 0..1 x nt 0..3) of chunk g land on XCD g%8 -> L2-shared W and Xb.
// ---------------------------------------------------------------------------
__global__ __launch_bounds__(256) void k2_gemm1(const unsigned short* __restrict__ Xb,
                                                const float* __restrict__ WL,
                                                const float* __restrict__ WR,
                                                unsigned short* __restrict__ P16) {
    const int d = blockIdx.x;
    const int g = d & 127;
    if (g >= 2 * G1_S) return;
    const int slot = d >> 7;       // 0..7
    const int mt = slot >> 2;      // 0..1
    const int nt = slot & 3;       // 0..3
    const int sc   = g >> 1;       // 0..57
    const int comp = g & 1;
    const int K      = comp ? KR : KL;
    const float* W   = comp ? WR : WL;
    const int xbase  = comp ? KL : 0;
    const int m0 = mt * 128;
    const int n0 = nt * 128;

    __shared__ unsigned short As[128 * 64];   // 16 KB
    __shared__ unsigned short Bs[128 * 64];   // 16 KB

    const int t = threadIdx.x, lane = t & 63, wid = t >> 6;
    const int wm = wid >> 1, wn = wid & 1;
    const int lr = lane & 15, lg = lane >> 4;

    f32x4 acc[4][4];
    #pragma unroll
    for (int i = 0; i < 4; ++i)
        #pragma unroll
        for (int j = 0; j < 4; ++j) {
            f32x4 z = {0.f, 0.f, 0.f, 0.f};
            acc[i][j] = z;
        }

    const int nsteps = (comp && sc == G1_S - 1) ? 9 : 8;

    // A staging: row am (0..127), 32-k segment aseg
    const int am = t >> 1, aseg = t & 1;
    const int arow = (m0 + am < N_ENC) ? (m0 + am) : (N_ENC - 1);
    const float* wrow = W + (size_t)arow * K;
    const int akey = (am & 7) << 3;
    // B staging: k-quad kq (0..15 -> 4 rows), col thread tc (0..15 -> 8 cols)
    const int kq = t >> 4, tc = t & 15;

    u16x8 ha[4];
    u16x8 hb4[4];

    auto load_tiles = [&](int st) {
        const int k0 = sc * 512 + st * 64;
        // ---- A: 32 k per thread (f32 -> bf16) ----
        {
            const int kb = k0 + aseg * 32;
            float av[32];
            if (kb + 31 < K) {
                #pragma unroll
                for (int f = 0; f < 8; ++f) {
                    const float4 v = *(const float4*)(wrow + kb + f * 4);
                    av[f * 4 + 0] = v.x; av[f * 4 + 1] = v.y;
                    av[f * 4 + 2] = v.z; av[f * 4 + 3] = v.w;
                }
            } else {
                #pragma unroll
                for (int j = 0; j < 32; ++j)
                    av[j] = (kb + j < K) ? wrow[kb + j] : 0.0f;
            }
            #pragma unroll
            for (int q = 0; q < 4; ++q) {
                u16x8 hh;
                #pragma unroll
                for (int j = 0; j < 8; ++j) hh[j] = cvt1(av[q * 8 + j]);
                ha[q] = hh;
            }
        }
        // ---- B: 4 k-rows x 8 cols per thread, straight bf16 loads ----
        #pragma unroll
        for (int r = 0; r < 4; ++r) {
            const int krel = k0 + kq * 4 + r;
            if (krel < K) {
                hb4[r] = *(const u16x8*)(Xb + (size_t)(xbase + krel) * T_PAD + n0 + tc * 8);
            } else {
                u16x8 z = {0, 0, 0, 0, 0, 0, 0, 0};
                hb4[r] = z;
            }
        }
    };

    auto write_stage = [&]() {
        #pragma unroll
        for (int q = 0; q < 4; ++q)
            *(u16x8*)&As[am * 64 + ((aseg * 32 + q * 8) ^ akey)] = ha[q];
        #pragma unroll
        for (int j = 0; j < 8; ++j) {
            const int nl = tc * 8 + j;
            const int key = ((nl ^ (nl >> 3)) & 7) << 3;
            u16x4 w4 = { hb4[0][j], hb4[1][j], hb4[2][j], hb4[3][j] };
            *(u16x4*)&Bs[nl * 64 + ((kq * 4) ^ key)] = w4;
        }
    };

    load_tiles(0);
    for (int st = 0; st < nsteps; ++st) {
        write_stage();
        __syncthreads();
        if (st + 1 < nsteps) load_tiles(st + 1);   // loads in flight during MFMA
        #pragma unroll
        for (int h = 0; h < 2; ++h) {
            u16x8 af[4], bf[4];
            #pragma unroll
            for (int mf = 0; mf < 4; ++mf) {
                const int m = wm * 64 + mf * 16 + lr;
                af[mf] = *(const u16x8*)&As[m * 64 + ((h * 32 + lg * 8) ^ ((m & 7) << 3))];
            }
            #pragma unroll
            for (int nf = 0; nf < 4; ++nf) {
                const int nl = wn * 64 + nf * 16 + lr;
                const int key = ((nl ^ (nl >> 3)) & 7) << 3;
                bf[nf] = *(const u16x8*)&Bs[nl * 64 + ((h * 32 + lg * 8) ^ key)];
            }
            #pragma unroll
            for (int mf = 0; mf < 4; ++mf)
                #pragma unroll
                for (int nf = 0; nf < 4; ++nf)
                    acc[mf][nf] = mfma16(af[mf], bf[nf], acc[mf][nf]);
        }
        __syncthreads();
    }

    unsigned short* Pb = P16 + (size_t)g * (200 * 512);
    #pragma unroll
    for (int mf = 0; mf < 4; ++mf)
        #pragma unroll
        for (int rr = 0; rr < 4; ++rr) {
            const int m = m0 + wm * 64 + mf * 16 + lg * 4 + rr;
            if (m < N_ENC) {
                #pragma unroll
                for (int nf = 0; nf < 4; ++nf) {
                    const int n = n0 + wn * 64 + nf * 16 + lr;
                    Pb[(size_t)m * 512 + n] = cvt1(acc[mf][nf][rr]);
                }
            }
        }
}

// ---------------------------------------------------------------------------
// K3: sum bf16 split-K partials (slice = s2*2 + comp) -> raw A row;
// store RAW bf16 Ab [512][512] (pad zero) + astat=(mu, 1/||Ac||).
// ---------------------------------------------------------------------------
__global__ __launch_bounds__(256) void k3_astats(const unsigned short* __restrict__ P16,
                                                 unsigned short* __restrict__ Ab,
                                                 float2* __restrict__ astat) {
    const int r = blockIdx.x;   // 0..511
    const int t = threadIdx.x;  // 0..255
    unsigned short* out = Ab + (size_t)r * T_PAD;
    if (r >= 2 * N_ENC) {
        out[t] = 0; out[t + 256] = 0;
        if (t == 0) astat[r] = make_float2(0.0f, 0.0f);
        return;
    }
    const int comp = (r >= N_ENC) ? 1 : 0;
    const int m = r - comp * N_ENC;
    float a1 = 0.0f, a2 = 0.0f;
    for (int s2 = 0; s2 < G1_S; ++s2) {
        const unsigned short* Pb = P16 + ((size_t)(s2 * 2 + comp) * 200 + m) * 512;
        a1 += bf2f(Pb[t]);
        a2 += bf2f(Pb[t + 256]);
    }
    const bool v2ok = (t + 256) < T_DIM;
    const float b2 = v2ok ? a2 : 0.0f;
    float s = a1 + b2;
    float q = a1 * a1 + b2 * b2;
    #pragma unroll
    for (int off = 32; off; off >>= 1) {
        s += __shfl_xor(s, off);
        q += __shfl_xor(q, off);
    }
    __shared__ float ls[4], lq[4];
    if ((t & 63) == 0) { ls[t >> 6] = s; lq[t >> 6] = q; }
    __syncthreads();
    const float S = ls[0] + ls[1] + ls[2] + ls[3];
    const float Q = lq[0] + lq[1] + lq[2] + lq[3];
    const float mean = S * (1.0f / 500.0f);
    const float iv   = rsqrtf(Q - 500.0f * mean * mean);
    out[t] = cvt1(a1);
    out[t + 256] = v2ok ? cvt1(a2) : (unsigned short)0;
    if (t == 0) astat[r] = make_float2(mean, iv);
}

// ---------------------------------------------------------------------------
// K4: G = Ab @ Xb^T (raw), epilogue C = (G - 500*muA*muX)*invA*invX.
// Tile 128m x 128j, 256 thr, swizzled LDS (FIXED key (row&7)<<3) +
// reg prefetch. Grid 1888 XCD-grouped: jt=(d>>5)*8+(d&7), mt=(d>>3)&3
// -> the 4 mt partners of a jt share an XCD (Xb tile L2 reuse).
// ---------------------------------------------------------------------------
__global__ __launch_bounds__(256, 3) void k4_gemm2(const unsigned short* __restrict__ Ab,
                                                   const unsigned short* __restrict__ Xb,
                                                   const float2* __restrict__ astat,
                                                   const float2* __restrict__ xstat,
                                                   float* __restrict__ C) {
    const int d  = blockIdx.x;
    const int jt = (d >> 5) * 8 + (d & 7);
    if (jt >= 465) return;
    const int mt = (d >> 3) & 3;
    const int j0 = jt * 128;
    const int m0 = mt * 128;

    __shared__ unsigned short As[128 * 64];
    __shared__ unsigned short Bs[128 * 64];
    const int t = threadIdx.x, lane = t & 63;
    const int wm = (t >> 6) >> 1, wnn = (t >> 6) & 1;
    const int lg = lane >> 4, lr = lane & 15;

    f32x4 acc[4][4];
    #pragma unroll
    for (int i = 0; i < 4; ++i)
        #pragma unroll
        for (int j = 0; j < 4; ++j) {
            f32x4 z = {0.f, 0.f, 0.f, 0.f};
            acc[i][j] = z;
        }

    const int ar = t >> 1, aseg = t & 1;
    const unsigned short* ag = Ab + (size_t)(m0 + ar) * T_PAD + aseg * 32;
    const unsigned short* bg = Xb + (size_t)(j0 + ar) * T_PAD + aseg * 32;
    const int akey = (ar & 7) << 3;

    u16x8 ha[4], hb[4];
    auto load4 = [&](int k0, u16x8 (&la)[4], u16x8 (&lb)[4]) {
        #pragma unroll
        for (int q = 0; q < 4; ++q) la[q] = *(const u16x8*)(ag + k0 + q * 8);
        #pragma unroll
        for (int q = 0; q < 4; ++q) lb[q] = *(const u16x8*)(bg + k0 + q * 8);
    };
    load4(0, ha, hb);

    for (int st = 0; st < 8; ++st) {
        #pragma unroll
        for (int q = 0; q < 4; ++q) {
            const int off = ar * 64 + ((aseg * 32 + q * 8) ^ akey);
            *(u16x8*)&As[off] = ha[q];
            *(u16x8*)&Bs[off] = hb[q];
        }
        __syncthreads();
        u16x8 na[4], nb[4];
        const bool more = st < 7;
        if (more) load4((st + 1) * 64, na, nb);
        #pragma unroll
        for (int h = 0; h < 2; ++h) {
            u16x8 bf4[4];
            #pragma unroll
            for (int nf = 0; nf < 4; ++nf) {
                const int n = wnn * 64 + nf * 16 + lr;
                bf4[nf] = *(const u16x8*)&Bs[n * 64 + ((h * 32 + lg * 8) ^ ((n & 7) << 3))];
            }
            #pragma unroll
            for (int mf = 0; mf < 4; ++mf) {
                const int m = wm * 64 + mf * 16 + lr;
                const u16x8 af = *(const u16x8*)&As[m * 64 + ((h * 32 + lg * 8) ^ ((m & 7) << 3))];
                #pragma unroll
                for (int nf = 0; nf < 4; ++nf)
                    acc[mf][nf] = mfma16(af, bf4[nf], acc[mf][nf]);
            }
        }
        __syncthreads();
        if (more) {
            #pragma unroll
            for (int q = 0; q < 4; ++q) { ha[q] = na[q]; hb[q] = nb[q]; }
        }
    }

    #pragma unroll
    for (int mf = 0; mf < 4; ++mf) {
        const int row = m0 + wm * 64 + mf * 16 + lg * 4;
        #pragma unroll
        for (int nf = 0; nf < 4; ++nf) {
            const int col = j0 + wnn * 64 + nf * 16 + lr;
            if (col < N_LOCI) {
                const float2 xs = xstat[col];
                #pragma unroll
                for (int rr = 0; rr < 4; ++rr) {
                    if (row + rr < 2 * N_ENC) {
                        const float2 as = astat[row + rr];
                        C[(size_t)(row + rr) * N_LOCI + col] =
                            (acc[mf][nf][rr] - 500.0f * as.x * xs.x) * as.y * xs.y;
                    }
                }
            }
        }
    }
}

// ---------------------------------------------------------------------------
extern "C" void kernel_launch(void* const* d_in, const int* in_sizes, int n_in,
                              void* d_out, int out_size, void* d_ws, size_t ws_size,
                              hipStream_t stream) {
    const float* X  = (const float*)d_in[0];
    const float* WL = (const float*)d_in[1];
    const float* WR = (const float*)d_in[2];
    float* C = (float*)d_out;

    // workspace (total ~85.8 MB):
    //   Xb    u16 [59648][512]     : 61,079,552 B
    //   P16   u16 [116][200][512]  : 23,756,800 B
    //   Ab    u16 [512][512]       :    524,288 B
    //   astat f32x2 [512]          :      4,096 B
    //   xstat f32x2 [59648]        :    477,184 B
    char* w = (char*)d_ws;
    unsigned short* Xb  = (unsigned short*)w;  w += (size_t)J_PAD * T_PAD * 2;
    unsigned short* P16 = (unsigned short*)w;  w += (size_t)2 * G1_S * 200 * 512 * 2;
    unsigned short* Ab  = (unsigned short*)w;  w += (size_t)512 * 512 * 2;
    float2* astat = (float2*)w;                w += (size_t)512 * 8;
    float2* xstat = (float2*)w;

    k0_xraw<<<dim3(J_PAD / 16), dim3(256), 0, stream>>>(X, Xb, xstat);
    k2_gemm1<<<dim3(1024), dim3(256), 0, stream>>>(Xb, WL, WR, P16);
    k3_astats<<<dim3(512), dim3(256), 0, stream>>>(P16, Ab, astat);
    k4_gemm2<<<dim3(1888), dim3(256), 0, stream>>>(Ab, Xb, astat, xstat, C);
}